// Round 21
// baseline (343.864 us; speedup 1.0000x reference)
//
#include <hip/hip_runtime.h>
#include <hip/hip_bf16.h>
#include <stdint.h>

#define TOKENS 4096
#define IN_F   4096
#define OUT_F  11008
#define PACKS  512          // IN_F/8
#define GCOUNT 32           // IN_F/128

#define BM 256
#define BN 256
#define BK 128
#define NKT (IN_F / BK)     // 32

typedef __attribute__((ext_vector_type(8))) short bf16x8;
typedef __attribute__((ext_vector_type(4))) float f32x4;
typedef __attribute__((ext_vector_type(4))) int i32x4;

#define AS1 __attribute__((address_space(1)))
#define AS3 __attribute__((address_space(3)))

static __device__ __forceinline__ short f2bf(float f) {
    union { __hip_bfloat16 h; short s; } u;
    u.h = __float2bfloat16(f);
    return u.s;
}

// ---------------- pre-pass 1: x fp32 -> i8 per-row (sx[row] = amax/127) ----------------
__global__ __launch_bounds__(256) void quant_x_kernel(const float* __restrict__ x,
                                                      signed char* __restrict__ xq,
                                                      float* __restrict__ sx) {
    const int row = blockIdx.x;
    const int t = threadIdx.x;
    const float4* src = (const float4*)(x + (size_t)row * IN_F);
    float4 v[4];
    float am = 0.0f;
#pragma unroll
    for (int i = 0; i < 4; ++i) {
        v[i] = src[t + 256 * i];
        am = fmaxf(am, fmaxf(fmaxf(fabsf(v[i].x), fabsf(v[i].y)),
                             fmaxf(fabsf(v[i].z), fabsf(v[i].w))));
    }
#pragma unroll
    for (int off = 32; off >= 1; off >>= 1)
        am = fmaxf(am, __shfl_xor(am, off));
    __shared__ float wmax[4];
    if ((t & 63) == 0) wmax[t >> 6] = am;
    __syncthreads();
    float amax = fmaxf(fmaxf(wmax[0], wmax[1]), fmaxf(wmax[2], wmax[3]));
    amax = fmaxf(amax, 1e-20f);
    const float rs = 127.0f / amax;
    int* dst = (int*)(xq + (size_t)row * IN_F);
#pragma unroll
    for (int i = 0; i < 4; ++i) {
        float fv[4] = {v[i].x, v[i].y, v[i].z, v[i].w};
        int p = 0;
#pragma unroll
        for (int j = 0; j < 4; ++j) {
            int q = __float2int_rn(fv[j] * rs);
            q = max(-127, min(127, q));
            p |= (q & 255) << (8 * j);
        }
        dst[t + 256 * i] = p;
    }
    if (t == 0) sx[row] = amax * (1.0f / 127.0f);
}

// ---------------- pre-pass 2: per-column W scale Sw[o] = max_g s*max(z,15-z) / 127 ----------------
__global__ __launch_bounds__(256) void sw_kernel(const int* __restrict__ qz,
                                                 const float* __restrict__ sc,
                                                 float* __restrict__ sw,
                                                 float* __restrict__ rw) {
    int o = blockIdx.x * 256 + threadIdx.x;      // 43*256 == 11008 exactly
    float wmax = 0.f;
#pragma unroll 8
    for (int g = 0; g < GCOUNT; ++g) {
        float s = sc[(size_t)g * OUT_F + o];
        int z = qz[(size_t)g * OUT_F + o];
        float m = (float)max(z, 15 - z);
        wmax = fmaxf(wmax, s * m);
    }
    sw[o] = wmax * (1.0f / 127.0f);
    rw[o] = 127.0f / wmax;
}

// ---------------- pre-pass 3: W8[o,k] = round((q-z)*s[g,o]/Sw[o]) in [-127,127] ----------------
__global__ __launch_bounds__(256) void quant_w8_kernel(const int* __restrict__ qw,
                                                       const int* __restrict__ qz,
                                                       const float* __restrict__ sc,
                                                       const float* __restrict__ rw,
                                                       signed char* __restrict__ wq) {
    int i = blockIdx.x * 256 + threadIdx.x;   // pack index: o*512 + p
    int o = i >> 9, p = i & 511, g = p >> 4;
    int z = qz[(size_t)g * OUT_F + o];
    float f = sc[(size_t)g * OUT_F + o] * rw[o];
    int w = qw[i];
    int lo = 0, hi = 0;
#pragma unroll
    for (int j = 0; j < 4; ++j) {
        int d = __float2int_rn((float)(((w >> (4 * j)) & 15) - z) * f);
        d = max(-127, min(127, d));
        lo |= (d & 255) << (8 * j);
    }
#pragma unroll
    for (int j = 4; j < 8; ++j) {
        int d = __float2int_rn((float)(((w >> (4 * j)) & 15) - z) * f);
        d = max(-127, min(127, d));
        hi |= (d & 255) << (8 * (j - 4));
    }
    ((int2*)wq)[i] = make_int2(lo, hi);
}

// ---------------- staging: i8 A-tile 256 rows x 128, 16B chunks, XOR-swizzled source ----------------
// LDS position (r, c) holds logical chunk c ^ (r&7); reader applies the same XOR.
__device__ __forceinline__ void stage_i8(const signed char* __restrict__ G, int grow0,
                                         int kt, signed char* lds, int tid) {
#pragma unroll
    for (int i = 0; i < 4; ++i) {
        int CH = i * 512 + tid;                  // chunk 0..2047
        int r = CH >> 3;
        int c = (CH & 7) ^ (r & 7);              // inverse swizzle on SOURCE
        const signed char* g = G + (size_t)(grow0 + r) * IN_F + kt + c * 16;
        __builtin_amdgcn_global_load_lds((const AS1 void*)g,
                                         (AS3 void*)(lds + CH * 16), 16, 0, 0);
    }
}

#define QUADI(AF, BF, AO, BO)                                                   \
    __builtin_amdgcn_s_setprio(1);                                              \
    _Pragma("unroll") for (int m = 0; m < 4; ++m)                               \
    _Pragma("unroll") for (int n = 0; n < 2; ++n)                               \
    _Pragma("unroll") for (int ks = 0; ks < 2; ++ks)                            \
        iacc[(AO) + m][(BO) + n] = __builtin_amdgcn_mfma_i32_16x16x64_i8(       \
            AF[m][ks], BF[n][ks], iacc[(AO) + m][(BO) + n], 0, 0, 0);           \
    __builtin_amdgcn_s_setprio(0);

// ---------------- i8 GEMM v21: A via LDS, B DIRECT from global (L2/L3) ----------------
// v20's WAR bug fixed: bf regs are overwritten only AFTER their consuming quad.
//  s0: read afA(t) ds; Q2(t-1) [bfA(t-1)]; THEN issue bfA(t)   (WAR-safe)
//  s1: Q3(t-1) [bfB(t-1)]; THEN issue bfB(t)
//  s2: read afB(t) ds; lgkm(8)+vmcnt(4) [afA,bfA ready]; Q0(t); lgkm(0); BAR [a]
//  s3: stage A(t+2); vmcnt(4|0) [bfB ready]; Q1(t); BAR [b]
// vmcnt ledger (in-order queue), steady state:
//  s2: [Ast(t+1)4, bfA4, bfB4] -> vmcnt(4) drains Ast+bfA (t=NKT-1: [bfA4,bfB4] -> same)
//  s3: [bfB4, Ast(t+2)4?] -> vmcnt(4) if t+2<NKT else vmcnt(0)
// bn-major XCD swizzle keeps each XCD's B panels L2-hot; wq (45 MB) is L3-resident.
__global__ __launch_bounds__(512, 2) void gemm_i8_kernel(const signed char* __restrict__ A,
                                                         const signed char* __restrict__ B,
                                                         const float* __restrict__ sw,
                                                         const float* __restrict__ sx,
                                                         float* __restrict__ C) {
    __shared__ signed char As[2][BM * BK];   // 2 x 32 KB (64 KB total)

    const int nbm = TOKENS / BM;             // 16
    const int nwg = nbm * (OUT_F / BN);      // 688 = 8*86
    const int cpx = nwg >> 3;                // 86
    int bid = blockIdx.x;
    int swzb = (bid & 7) * cpx + (bid >> 3); // XCD-contiguous (bijective)
    int bn = swzb / nbm, bm = swzb % nbm;    // bn-major: same-bn runs share B panel in L2
    const int row0 = bm * BM, col0 = bn * BN;

    const int tid = threadIdx.x;
    const int lane = tid & 63;
    const int wid = tid >> 6;                // 8 waves: 2M x 4N
    const int wm = wid >> 2, wn = wid & 3;
    const int l15 = lane & 15, lhi = lane >> 4, l7 = lane & 7;
    const int cs0 = ((lhi ^ l7) & 7) * 16;        // ks0 chunk byte offset (LDS A)
    const int cs1 = (((4 + lhi) ^ l7) & 7) * 16;  // ks1
    const int rdA = (wm * 128 + l15) * BK;        // bytes; + m*2048 + cs

    // B direct-load base: row (col0 + wn*64 + n*16 + l15), k = t*BK + lhi*16 (+64 ks1)
    const signed char* Bbase = B + (size_t)(col0 + wn * 64 + l15) * IN_F + lhi * 16;

    i32x4 iacc[8][4] = {};
    i32x4 afA[4][2], afB[4][2], bfA[2][2], bfB[2][2];

    // prologue: stage A(0)->As[0], A(1)->As[1]; wait A(0) landed (A(1) in flight)
    stage_i8(A, row0, 0, &As[0][0], tid);
    stage_i8(A, row0, BK, &As[1][0], tid);
    asm volatile("s_waitcnt vmcnt(4)" ::: "memory");
    __builtin_amdgcn_s_barrier();

    for (int t = 0; t < NKT; ++t) {
        const int cab = t & 1;
        const signed char* At = &As[cab][0];
        const size_t kb = (size_t)t * BK;

        // ---- s0: read afA(t); Q2(t-1); issue bfA(t) (after its consumer) ----
#pragma unroll
        for (int m = 0; m < 4; ++m) {
            afA[m][0] = *(const i32x4*)(At + rdA + m * 2048 + cs0);
            afA[m][1] = *(const i32x4*)(At + rdA + m * 2048 + cs1);
        }
        __builtin_amdgcn_sched_barrier(0);
        if (t > 0) { QUADI(afB, bfA, 4, 0); }
        __builtin_amdgcn_sched_barrier(0);
#pragma unroll
        for (int n = 0; n < 2; ++n) {
            bfA[n][0] = *(const i32x4*)(Bbase + (size_t)(n * 16) * IN_F + kb);
            bfA[n][1] = *(const i32x4*)(Bbase + (size_t)(n * 16) * IN_F + kb + 64);
        }
        __builtin_amdgcn_sched_barrier(0);

        // ---- s1: Q3(t-1); issue bfB(t) (after its consumer) ----
        if (t > 0) { QUADI(afB, bfB, 4, 2); }
        __builtin_amdgcn_sched_barrier(0);
#pragma unroll
        for (int n = 0; n < 2; ++n) {
            bfB[n][0] = *(const i32x4*)(Bbase + (size_t)((2 + n) * 16) * IN_F + kb);
            bfB[n][1] = *(const i32x4*)(Bbase + (size_t)((2 + n) * 16) * IN_F + kb + 64);
        }
        __builtin_amdgcn_sched_barrier(0);

        // ---- s2: read afB(t); wait afA+bfA; Q0(t); lgkm(0); BAR [fence a] ----
#pragma unroll
        for (int m = 0; m < 4; ++m) {
            afB[m][0] = *(const i32x4*)(At + rdA + (4 + m) * 2048 + cs0);
            afB[m][1] = *(const i32x4*)(At + rdA + (4 + m) * 2048 + cs1);
        }
        __builtin_amdgcn_sched_barrier(0);
        asm volatile("s_waitcnt lgkmcnt(8)" ::: "memory");   // afA(t) done
        asm volatile("s_waitcnt vmcnt(4)" ::: "memory");     // bfA(t) done (bfB in flight)
        __builtin_amdgcn_sched_barrier(0);
        QUADI(afA, bfA, 0, 0);
        asm volatile("s_waitcnt lgkmcnt(0)" ::: "memory");   // all As[cab] ds reads done
        __builtin_amdgcn_sched_barrier(0);
        __builtin_amdgcn_s_barrier();

        // ---- s3: stage A(t+2)->As[cab]; wait bfB; Q1(t); BAR [fence b] ----
        if (t + 2 < NKT) stage_i8(A, row0, (t + 2) * BK, &As[cab][0], tid);
        __builtin_amdgcn_sched_barrier(0);
        if (t + 2 < NKT) {
            asm volatile("s_waitcnt vmcnt(4)" ::: "memory");     // bfB(t) done; Ast(t+2) flying
        } else {
            asm volatile("s_waitcnt vmcnt(0)" ::: "memory");     // tails: everything done
        }
        __builtin_amdgcn_sched_barrier(0);
        QUADI(afA, bfB, 0, 2);
        __builtin_amdgcn_sched_barrier(0);
        __builtin_amdgcn_s_barrier();
    }

    // ---- pipeline tail: Q2(31), Q3(31) (bf(31) drained by vmcnt(0) in last s3) ----
    { QUADI(afB, bfA, 4, 0); }
    { QUADI(afB, bfB, 4, 2); }

    // ---- epilogue: C = sx[row] * Sw[col] * iacc ----
#pragma unroll
    for (int m = 0; m < 8; ++m) {
        const int rbase = row0 + wm * 128 + m * 16 + lhi * 4;
        f32x4 s4 = *(const f32x4*)(sx + rbase);
#pragma unroll
        for (int n = 0; n < 4; ++n) {
            const int c = col0 + wn * 64 + n * 16 + l15;
            const float swc = sw[c];
#pragma unroll
            for (int j = 0; j < 4; ++j)
                C[(size_t)(rbase + j) * OUT_F + c] = s4[j] * swc * (float)iacc[m][n][j];
        }
    }
}

// ---------------- fallback: fused dequant GEMM (128-tile bf16, known-good) ----------------
__device__ __forceinline__ void mfma_tile128(const short* As, const short* Bs,
                                             f32x4 acc[4][4], int lane, int wm, int wn) {
#pragma unroll
    for (int kk = 0; kk < 64; kk += 32) {
        const int kb = kk + (lane >> 4) * 8;
        bf16x8 af[4], bfr[4];
#pragma unroll
        for (int m = 0; m < 4; ++m) {
            int r = wm * 64 + m * 16 + (lane & 15);
            af[m] = *(const bf16x8*)(As + r * 64 + kb);
        }
#pragma unroll
        for (int n = 0; n < 4; ++n) {
            int c = wn * 64 + n * 16 + (lane & 15);
            bfr[n] = *(const bf16x8*)(Bs + c * 64 + kb);
        }
#pragma unroll
        for (int m = 0; m < 4; ++m)
#pragma unroll
            for (int n = 0; n < 4; ++n)
                acc[m][n] = __builtin_amdgcn_mfma_f32_16x16x32_bf16(af[m], bfr[n],
                                                                    acc[m][n], 0, 0, 0);
    }
}

__global__ __launch_bounds__(256) void gemm_fused_kernel(const float* __restrict__ x,
                                                         const int* __restrict__ qw,
                                                         const int* __restrict__ qz,
                                                         const float* __restrict__ sc,
                                                         float* __restrict__ C) {
    const int nbn = OUT_F / 128;
    const int nwg = (TOKENS / 128) * nbn;
    const int cpx = nwg >> 3;
    int bid = blockIdx.x;
    int swzb = (bid & 7) * cpx + (bid >> 3);
    int bm = swzb / nbn, bn = swzb % nbn;
    const int row0 = bm * 128, col0 = bn * 128;

    __shared__ short As[128 * 64];
    __shared__ short Bs[128 * 64];

    const int tid = threadIdx.x;
    const int lane = tid & 63;
    const int wid = tid >> 6;
    const int wm = wid >> 1, wn = wid & 1;

    f32x4 acc[4][4] = {};

    for (int kt = 0; kt < IN_F; kt += 64) {
#pragma unroll
        for (int i = 0; i < 4; ++i) {
            int idx = i * 256 + tid;
            int r = idx >> 3, kc = (idx & 7) * 8;
            const float4* src = (const float4*)(x + (size_t)(row0 + r) * IN_F + kt + kc);
            float4 aa = src[0], bb = src[1];
            bf16x8 v;
            v[0] = f2bf(aa.x); v[1] = f2bf(aa.y); v[2] = f2bf(aa.z); v[3] = f2bf(aa.w);
            v[4] = f2bf(bb.x); v[5] = f2bf(bb.y); v[6] = f2bf(bb.z); v[7] = f2bf(bb.w);
            *(bf16x8*)(As + r * 64 + kc) = v;
        }
        {
            int ol = tid >> 1;
            int kc = (tid & 1) * 32;
            const int4* src = (const int4*)(qw + (size_t)(col0 + ol) * PACKS + ((kt + kc) >> 3));
            int4 w4 = *src;
            int g = kt >> 7;
            float z = (float)qz[(size_t)g * OUT_F + col0 + ol];
            float s = sc[(size_t)g * OUT_F + col0 + ol];
            float zs = z * s;
            const int* wp = (const int*)&w4;
#pragma unroll
            for (int c2 = 0; c2 < 4; ++c2) {
                int w32 = wp[c2];
                bf16x8 v;
#pragma unroll
                for (int j = 0; j < 8; ++j)
                    v[j] = f2bf((float)((w32 >> (4 * j)) & 15) * s - zs);
                *(bf16x8*)(Bs + ol * 64 + kc + c2 * 8) = v;
            }
        }
        __syncthreads();
        mfma_tile128(As, Bs, acc, lane, wm, wn);
        __syncthreads();
    }
#pragma unroll
    for (int m = 0; m < 4; ++m)
#pragma unroll
        for (int n = 0; n < 4; ++n) {
            int r = row0 + wm * 64 + m * 16 + ((lane >> 4) << 2);
            int c = col0 + wn * 64 + n * 16 + (lane & 15);
#pragma unroll
            for (int j = 0; j < 4; ++j)
                C[(size_t)(r + j) * OUT_F + c] = acc[m][n][j];
        }
}

extern "C" void kernel_launch(void* const* d_in, const int* in_sizes, int n_in,
                              void* d_out, int out_size, void* d_ws, size_t ws_size,
                              hipStream_t stream) {
    const float* x = (const float*)d_in[0];
    const int* qw = (const int*)d_in[1];
    const int* qz = (const int*)d_in[2];
    const float* sc = (const float*)d_in[3];
    float* out = (float*)d_out;

    const size_t xq_b = (size_t)TOKENS * IN_F;       // 16 MB
    const size_t sx_b = (size_t)TOKENS * 4;          // 16 KB
    const size_t sw_b = (size_t)OUT_F * 4;           // 44 KB
    const size_t wq_b = (size_t)OUT_F * IN_F;        // 45 MB
    const size_t need = xq_b + sx_b + 2 * sw_b + wq_b;

    if (ws_size >= need) {
        signed char* xq = (signed char*)d_ws;
        float* sx = (float*)((char*)d_ws + xq_b);
        float* sw = (float*)((char*)d_ws + xq_b + sx_b);
        float* rw = (float*)((char*)d_ws + xq_b + sx_b + sw_b);
        signed char* wq = (signed char*)((char*)d_ws + xq_b + sx_b + 2 * sw_b);
        quant_x_kernel<<<TOKENS, 256, 0, stream>>>(x, xq, sx);
        sw_kernel<<<OUT_F / 256, 256, 0, stream>>>(qz, sc, sw, rw);
        quant_w8_kernel<<<(OUT_F * PACKS) / 256, 256, 0, stream>>>(qw, qz, sc, rw, wq);
        const int ngemm = (TOKENS / BM) * (OUT_F / BN);   // 688
        gemm_i8_kernel<<<ngemm, 512, 0, stream>>>(xq, wq, sw, sx, out);
    } else {
        gemm_fused_kernel<<<(TOKENS / 128) * (OUT_F / 128), 256, 0, stream>>>(x, qw, qz, sc, out);
    }
}

// Round 22
// 257.544 us; speedup vs baseline: 1.3352x; 1.3352x over previous
//
#include <hip/hip_runtime.h>
#include <hip/hip_bf16.h>
#include <stdint.h>

#define TOKENS 4096
#define IN_F   4096
#define OUT_F  11008
#define PACKS  512          // IN_F/8
#define GCOUNT 32           // IN_F/128

#define BM 256
#define BN 256
#define BK 128
#define NKT (IN_F / BK)     // 32

typedef __attribute__((ext_vector_type(8))) short bf16x8;
typedef __attribute__((ext_vector_type(4))) float f32x4;
typedef __attribute__((ext_vector_type(4))) int i32x4;

#define AS1 __attribute__((address_space(1)))
#define AS3 __attribute__((address_space(3)))

static __device__ __forceinline__ short f2bf(float f) {
    union { __hip_bfloat16 h; short s; } u;
    u.h = __float2bfloat16(f);
    return u.s;
}

// ---------------- pre-pass 1: x fp32 -> i8 per-row (sx[row] = amax/127) ----------------
__global__ __launch_bounds__(256) void quant_x_kernel(const float* __restrict__ x,
                                                      signed char* __restrict__ xq,
                                                      float* __restrict__ sx) {
    const int row = blockIdx.x;
    const int t = threadIdx.x;
    const float4* src = (const float4*)(x + (size_t)row * IN_F);
    float4 v[4];
    float am = 0.0f;
#pragma unroll
    for (int i = 0; i < 4; ++i) {
        v[i] = src[t + 256 * i];
        am = fmaxf(am, fmaxf(fmaxf(fabsf(v[i].x), fabsf(v[i].y)),
                             fmaxf(fabsf(v[i].z), fabsf(v[i].w))));
    }
#pragma unroll
    for (int off = 32; off >= 1; off >>= 1)
        am = fmaxf(am, __shfl_xor(am, off));
    __shared__ float wmax[4];
    if ((t & 63) == 0) wmax[t >> 6] = am;
    __syncthreads();
    float amax = fmaxf(fmaxf(wmax[0], wmax[1]), fmaxf(wmax[2], wmax[3]));
    amax = fmaxf(amax, 1e-20f);
    const float rs = 127.0f / amax;
    int* dst = (int*)(xq + (size_t)row * IN_F);
#pragma unroll
    for (int i = 0; i < 4; ++i) {
        float fv[4] = {v[i].x, v[i].y, v[i].z, v[i].w};
        int p = 0;
#pragma unroll
        for (int j = 0; j < 4; ++j) {
            int q = __float2int_rn(fv[j] * rs);
            q = max(-127, min(127, q));
            p |= (q & 255) << (8 * j);
        }
        dst[t + 256 * i] = p;
    }
    if (t == 0) sx[row] = amax * (1.0f / 127.0f);
}

// ---------------- pre-pass 2: per-column W scale Sw[o] = max_g s*max(z,15-z) / 127 ----------------
__global__ __launch_bounds__(256) void sw_kernel(const int* __restrict__ qz,
                                                 const float* __restrict__ sc,
                                                 float* __restrict__ sw,
                                                 float* __restrict__ rw) {
    int o = blockIdx.x * 256 + threadIdx.x;      // 43*256 == 11008 exactly
    float wmax = 0.f;
#pragma unroll 8
    for (int g = 0; g < GCOUNT; ++g) {
        float s = sc[(size_t)g * OUT_F + o];
        int z = qz[(size_t)g * OUT_F + o];
        float m = (float)max(z, 15 - z);
        wmax = fmaxf(wmax, s * m);
    }
    sw[o] = wmax * (1.0f / 127.0f);
    rw[o] = 127.0f / wmax;
}

// ---------------- pre-pass 3: W8[o,k] = round((q-z)*s[g,o]/Sw[o]) in [-127,127] ----------------
__global__ __launch_bounds__(256) void quant_w8_kernel(const int* __restrict__ qw,
                                                       const int* __restrict__ qz,
                                                       const float* __restrict__ sc,
                                                       const float* __restrict__ rw,
                                                       signed char* __restrict__ wq) {
    int i = blockIdx.x * 256 + threadIdx.x;   // pack index: o*512 + p
    int o = i >> 9, p = i & 511, g = p >> 4;
    int z = qz[(size_t)g * OUT_F + o];
    float f = sc[(size_t)g * OUT_F + o] * rw[o];
    int w = qw[i];
    int lo = 0, hi = 0;
#pragma unroll
    for (int j = 0; j < 4; ++j) {
        int d = __float2int_rn((float)(((w >> (4 * j)) & 15) - z) * f);
        d = max(-127, min(127, d));
        lo |= (d & 255) << (8 * j);
    }
#pragma unroll
    for (int j = 4; j < 8; ++j) {
        int d = __float2int_rn((float)(((w >> (4 * j)) & 15) - z) * f);
        d = max(-127, min(127, d));
        hi |= (d & 255) << (8 * (j - 4));
    }
    ((int2*)wq)[i] = make_int2(lo, hi);
}

// ---------------- staging: i8 tile 256 rows x 128, 16B chunks, XOR-swizzled source ----------------
// LDS position (r, c) holds logical chunk c ^ (r&7); reader applies the same XOR.
__device__ __forceinline__ void stage_i8(const signed char* __restrict__ G, int grow0,
                                         int kt, signed char* lds, int tid) {
#pragma unroll
    for (int i = 0; i < 4; ++i) {
        int CH = i * 512 + tid;                  // chunk 0..2047
        int r = CH >> 3;
        int c = (CH & 7) ^ (r & 7);              // inverse swizzle on SOURCE
        const signed char* g = G + (size_t)(grow0 + r) * IN_F + kt + c * 16;
        __builtin_amdgcn_global_load_lds((const AS1 void*)g,
                                         (AS3 void*)(lds + CH * 16), 16, 0, 0);
    }
}

#define QUADI(AF, BF, AO, BO)                                                   \
    __builtin_amdgcn_s_setprio(1);                                              \
    _Pragma("unroll") for (int m = 0; m < 4; ++m)                               \
    _Pragma("unroll") for (int n = 0; n < 2; ++n)                               \
    _Pragma("unroll") for (int ks = 0; ks < 2; ++ks)                            \
        iacc[(AO) + m][(BO) + n] = __builtin_amdgcn_mfma_i32_16x16x64_i8(       \
            AF[m][ks], BF[n][ks], iacc[(AO) + m][(BO) + n], 0, 0, 0);           \
    __builtin_amdgcn_s_setprio(0);

// ---------------- i8 GEMM: 256x256, BK=128, 2 barriers/K-tile (settled best, r17) ----------------
// Quads: Q0=(m0-3,n0-1) Q1=(m0-3,n2-3) Q2=(m4-7,n0-1) Q3=(m4-7,n2-3), 16 MFMA each.
// Q2/Q3 of tile t run in sub0/sub1 of tile t+1 (read-ahead).
// Fence (a): afB read BEFORE bfB in sub2, so lgkmcnt(4) drains exactly the As[cab]
// readers while bfB(4) stays in flight (consumed by own-wave Q1 before fence (b)).
// Fence (b): vmcnt(4) => A(t+1),B(t+1) landed; A(t+2) in flight.
__global__ __launch_bounds__(512, 2) void gemm_i8_kernel(const signed char* __restrict__ A,
                                                         const signed char* __restrict__ B,
                                                         const float* __restrict__ sw,
                                                         const float* __restrict__ sx,
                                                         float* __restrict__ C) {
    __shared__ signed char As[2][BM * BK];   // 2 x 32 KB
    __shared__ signed char Bs[2][BN * BK];   // 2 x 32 KB (128 KB total)

    const int nbn = OUT_F / BN;              // 43
    const int nwg = (TOKENS / BM) * nbn;     // 688 = 8*86
    const int cpx = nwg >> 3;
    int bid = blockIdx.x;
    int swzb = (bid & 7) * cpx + (bid >> 3); // XCD-contiguous (bijective)
    int bm = swzb / nbn, bn = swzb % nbn;
    const int row0 = bm * BM, col0 = bn * BN;

    const int tid = threadIdx.x;
    const int lane = tid & 63;
    const int wid = tid >> 6;                // 8 waves: 2M x 4N
    const int wm = wid >> 2, wn = wid & 3;
    const int l15 = lane & 15, lhi = lane >> 4, l7 = lane & 7;
    const int cs0 = ((lhi ^ l7) & 7) * 16;        // ks0 chunk byte offset
    const int cs1 = (((4 + lhi) ^ l7) & 7) * 16;  // ks1
    const int rdA = (wm * 128 + l15) * BK;        // bytes; + m*2048 + cs
    const int rdB = (wn * 64 + l15) * BK;         // bytes; + n*2048 + cs

    i32x4 iacc[8][4] = {};
    i32x4 afA[4][2], afB[4][2], bfA[2][2], bfB[2][2];

    // prologue: A(0)->As[0], B(0)->Bs[0], A(1)->As[1]; A0,B0 landed, A1 in flight
    stage_i8(A, row0, 0, &As[0][0], tid);
    stage_i8(B, col0, 0, &Bs[0][0], tid);
    stage_i8(A, row0, BK, &As[1][0], tid);
    asm volatile("s_waitcnt vmcnt(4)" ::: "memory");
    __builtin_amdgcn_s_barrier();

    for (int t = 0; t < NKT; ++t) {
        const int cab = t & 1;
        const signed char* At = &As[cab][0];
        const signed char* Bt = &Bs[cab][0];

        // ---- sub0: read afA(t); stage B(t+1)->Bs[cab^1]; MFMA Q2(t-1) ----
#pragma unroll
        for (int m = 0; m < 4; ++m) {
            afA[m][0] = *(const i32x4*)(At + rdA + m * 2048 + cs0);
            afA[m][1] = *(const i32x4*)(At + rdA + m * 2048 + cs1);
        }
        if (t + 1 < NKT) stage_i8(B, col0, (t + 1) * BK, &Bs[cab ^ 1][0], tid);
        __builtin_amdgcn_sched_barrier(0);
        if (t > 0) { QUADI(afB, bfA, 4, 0); }

        // ---- sub1: read bfA(t); MFMA Q3(t-1) ----
#pragma unroll
        for (int n = 0; n < 2; ++n) {
            bfA[n][0] = *(const i32x4*)(Bt + rdB + n * 2048 + cs0);
            bfA[n][1] = *(const i32x4*)(Bt + rdB + n * 2048 + cs1);
        }
        __builtin_amdgcn_sched_barrier(0);
        if (t > 0) { QUADI(afB, bfB, 4, 2); }

        // ---- sub2: read afB(t) FIRST, then bfB(t); MFMA Q0(t); fence (a)=lgkmcnt(4) ----
#pragma unroll
        for (int m = 0; m < 4; ++m) {
            afB[m][0] = *(const i32x4*)(At + rdA + (4 + m) * 2048 + cs0);
            afB[m][1] = *(const i32x4*)(At + rdA + (4 + m) * 2048 + cs1);
        }
#pragma unroll
        for (int n = 0; n < 2; ++n) {
            bfB[n][0] = *(const i32x4*)(Bt + rdB + (2 + n) * 2048 + cs0);
            bfB[n][1] = *(const i32x4*)(Bt + rdB + (2 + n) * 2048 + cs1);
        }
        __builtin_amdgcn_sched_barrier(0);
        QUADI(afA, bfA, 0, 0);
        asm volatile("s_waitcnt lgkmcnt(4)" ::: "memory");   // drain afB; bfB may fly
        __builtin_amdgcn_sched_barrier(0);
        __builtin_amdgcn_s_barrier();

        // ---- sub3: stage A(t+2)->As[cab]; MFMA Q1(t); fence (b) ----
        if (t + 2 < NKT) stage_i8(A, row0, (t + 2) * BK, &As[cab][0], tid);
        __builtin_amdgcn_sched_barrier(0);
        QUADI(afA, bfB, 0, 2);
        if (t < NKT - 2) {
            asm volatile("s_waitcnt vmcnt(4)" ::: "memory");   // t+1 landed; A(t+2) in flight
        } else if (t == NKT - 2) {
            asm volatile("s_waitcnt vmcnt(0)" ::: "memory");
        }
        __builtin_amdgcn_s_barrier();
    }

    // ---- pipeline tail: Q2(31), Q3(31) ----
    { QUADI(afB, bfA, 4, 0); }
    { QUADI(afB, bfB, 4, 2); }

    // ---- epilogue: C = sx[row] * Sw[col] * iacc ----
#pragma unroll
    for (int m = 0; m < 8; ++m) {
        const int rbase = row0 + wm * 128 + m * 16 + lhi * 4;
        f32x4 s4 = *(const f32x4*)(sx + rbase);
#pragma unroll
        for (int n = 0; n < 4; ++n) {
            const int c = col0 + wn * 64 + n * 16 + l15;
            const float swc = sw[c];
#pragma unroll
            for (int j = 0; j < 4; ++j)
                C[(size_t)(rbase + j) * OUT_F + c] = s4[j] * swc * (float)iacc[m][n][j];
        }
    }
}

// ---------------- fallback: fused dequant GEMM (128-tile bf16, known-good) ----------------
__device__ __forceinline__ void mfma_tile128(const short* As, const short* Bs,
                                             f32x4 acc[4][4], int lane, int wm, int wn) {
#pragma unroll
    for (int kk = 0; kk < 64; kk += 32) {
        const int kb = kk + (lane >> 4) * 8;
        bf16x8 af[4], bfr[4];
#pragma unroll
        for (int m = 0; m < 4; ++m) {
            int r = wm * 64 + m * 16 + (lane & 15);
            af[m] = *(const bf16x8*)(As + r * 64 + kb);
        }
#pragma unroll
        for (int n = 0; n < 4; ++n) {
            int c = wn * 64 + n * 16 + (lane & 15);
            bfr[n] = *(const bf16x8*)(Bs + c * 64 + kb);
        }
#pragma unroll
        for (int m = 0; m < 4; ++m)
#pragma unroll
            for (int n = 0; n < 4; ++n)
                acc[m][n] = __builtin_amdgcn_mfma_f32_16x16x32_bf16(af[m], bfr[n],
                                                                    acc[m][n], 0, 0, 0);
    }
}

__global__ __launch_bounds__(256) void gemm_fused_kernel(const float* __restrict__ x,
                                                         const int* __restrict__ qw,
                                                         const int* __restrict__ qz,
                                                         const float* __restrict__ sc,
                                                         float* __restrict__ C) {
    const int nbn = OUT_F / 128;
    const int nwg = (TOKENS / 128) * nbn;
    const int cpx = nwg >> 3;
    int bid = blockIdx.x;
    int swzb = (bid & 7) * cpx + (bid >> 3);
    int bm = swzb / nbn, bn = swzb % nbn;
    const int row0 = bm * 128, col0 = bn * 128;

    __shared__ short As[128 * 64];
    __shared__ short Bs[128 * 64];

    const int tid = threadIdx.x;
    const int lane = tid & 63;
    const int wid = tid >> 6;
    const int wm = wid >> 1, wn = wid & 1;

    f32x4 acc[4][4] = {};

    for (int kt = 0; kt < IN_F; kt += 64) {
#pragma unroll
        for (int i = 0; i < 4; ++i) {
            int idx = i * 256 + tid;
            int r = idx >> 3, kc = (idx & 7) * 8;
            const float4* src = (const float4*)(x + (size_t)(row0 + r) * IN_F + kt + kc);
            float4 aa = src[0], bb = src[1];
            bf16x8 v;
            v[0] = f2bf(aa.x); v[1] = f2bf(aa.y); v[2] = f2bf(aa.z); v[3] = f2bf(aa.w);
            v[4] = f2bf(bb.x); v[5] = f2bf(bb.y); v[6] = f2bf(bb.z); v[7] = f2bf(bb.w);
            *(bf16x8*)(As + r * 64 + kc) = v;
        }
        {
            int ol = tid >> 1;
            int kc = (tid & 1) * 32;
            const int4* src = (const int4*)(qw + (size_t)(col0 + ol) * PACKS + ((kt + kc) >> 3));
            int4 w4 = *src;
            int g = kt >> 7;
            float z = (float)qz[(size_t)g * OUT_F + col0 + ol];
            float s = sc[(size_t)g * OUT_F + col0 + ol];
            float zs = z * s;
            const int* wp = (const int*)&w4;
#pragma unroll
            for (int c2 = 0; c2 < 4; ++c2) {
                int w32 = wp[c2];
                bf16x8 v;
#pragma unroll
                for (int j = 0; j < 8; ++j)
                    v[j] = f2bf((float)((w32 >> (4 * j)) & 15) * s - zs);
                *(bf16x8*)(Bs + ol * 64 + kc + c2 * 8) = v;
            }
        }
        __syncthreads();
        mfma_tile128(As, Bs, acc, lane, wm, wn);
        __syncthreads();
    }
#pragma unroll
    for (int m = 0; m < 4; ++m)
#pragma unroll
        for (int n = 0; n < 4; ++n) {
            int r = row0 + wm * 64 + m * 16 + ((lane >> 4) << 2);
            int c = col0 + wn * 64 + n * 16 + (lane & 15);
#pragma unroll
            for (int j = 0; j < 4; ++j)
                C[(size_t)(r + j) * OUT_F + c] = acc[m][n][j];
        }
}

extern "C" void kernel_launch(void* const* d_in, const int* in_sizes, int n_in,
                              void* d_out, int out_size, void* d_ws, size_t ws_size,
                              hipStream_t stream) {
    const float* x = (const float*)d_in[0];
    const int* qw = (const int*)d_in[1];
    const int* qz = (const int*)d_in[2];
    const float* sc = (const float*)d_in[3];
    float* out = (float*)d_out;

    const size_t xq_b = (size_t)TOKENS * IN_F;       // 16 MB
    const size_t sx_b = (size_t)TOKENS * 4;          // 16 KB
    const size_t sw_b = (size_t)OUT_F * 4;           // 44 KB
    const size_t wq_b = (size_t)OUT_F * IN_F;        // 45 MB
    const size_t need = xq_b + sx_b + 2 * sw_b + wq_b;

    if (ws_size >= need) {
        signed char* xq = (signed char*)d_ws;
        float* sx = (float*)((char*)d_ws + xq_b);
        float* sw = (float*)((char*)d_ws + xq_b + sx_b);
        float* rw = (float*)((char*)d_ws + xq_b + sx_b + sw_b);
        signed char* wq = (signed char*)((char*)d_ws + xq_b + sx_b + 2 * sw_b);
        quant_x_kernel<<<TOKENS, 256, 0, stream>>>(x, xq, sx);
        sw_kernel<<<OUT_F / 256, 256, 0, stream>>>(qz, sc, sw, rw);
        quant_w8_kernel<<<(OUT_F * PACKS) / 256, 256, 0, stream>>>(qw, qz, sc, rw, wq);
        const int ngemm = (TOKENS / BM) * (OUT_F / BN);   // 688
        gemm_i8_kernel<<<ngemm, 512, 0, stream>>>(xq, wq, sw, sx, out);
    } else {
        gemm_fused_kernel<<<(TOKENS / 128) * (OUT_F / 128), 256, 0, stream>>>(x, qw, qz, sc, out);
    }
}

// Round 23
// 249.181 us; speedup vs baseline: 1.3800x; 1.0336x over previous
//
#include <hip/hip_runtime.h>
#include <hip/hip_bf16.h>
#include <stdint.h>

#define TOKENS 4096
#define IN_F   4096
#define OUT_F  11008
#define PACKS  512          // IN_F/8
#define GCOUNT 32           // IN_F/128

#define BM 256
#define BN 256
#define BK 128
#define NKT (IN_F / BK)     // 32

typedef __attribute__((ext_vector_type(8))) short bf16x8;
typedef __attribute__((ext_vector_type(4))) float f32x4;
typedef __attribute__((ext_vector_type(4))) int i32x4;

#define AS1 __attribute__((address_space(1)))
#define AS3 __attribute__((address_space(3)))

static __device__ __forceinline__ short f2bf(float f) {
    union { __hip_bfloat16 h; short s; } u;
    u.h = __float2bfloat16(f);
    return u.s;
}

// ---------------- fused pre-pass: quant_x (blocks < TOKENS) + sw/quant_w8 (rest) ----------------
__global__ __launch_bounds__(256) void prep_kernel(const float* __restrict__ x,
                                                   const int* __restrict__ qw,
                                                   const int* __restrict__ qz,
                                                   const float* __restrict__ sc,
                                                   signed char* __restrict__ xq,
                                                   float* __restrict__ sx,
                                                   float* __restrict__ sw,
                                                   signed char* __restrict__ wq) {
    const int bid = blockIdx.x;
    const int t = threadIdx.x;
    if (bid < TOKENS) {
        // ---- quant_x: one row per block ----
        const int row = bid;
        const float4* src = (const float4*)(x + (size_t)row * IN_F);
        float4 v[4];
        float am = 0.0f;
#pragma unroll
        for (int i = 0; i < 4; ++i) {
            v[i] = src[t + 256 * i];
            am = fmaxf(am, fmaxf(fmaxf(fabsf(v[i].x), fabsf(v[i].y)),
                                 fmaxf(fabsf(v[i].z), fabsf(v[i].w))));
        }
#pragma unroll
        for (int off = 32; off >= 1; off >>= 1)
            am = fmaxf(am, __shfl_xor(am, off));
        __shared__ float wmaxs[4];
        if ((t & 63) == 0) wmaxs[t >> 6] = am;
        __syncthreads();
        float amax = fmaxf(fmaxf(wmaxs[0], wmaxs[1]), fmaxf(wmaxs[2], wmaxs[3]));
        amax = fmaxf(amax, 1e-20f);
        const float rs = 127.0f / amax;
        int* dst = (int*)(xq + (size_t)row * IN_F);
#pragma unroll
        for (int i = 0; i < 4; ++i) {
            float fv[4] = {v[i].x, v[i].y, v[i].z, v[i].w};
            int p = 0;
#pragma unroll
            for (int j = 0; j < 4; ++j) {
                int q = __float2int_rn(fv[j] * rs);
                q = max(-127, min(127, q));
                p |= (q & 255) << (8 * j);
            }
            dst[t + 256 * i] = p;
        }
        if (t == 0) sx[row] = amax * (1.0f / 127.0f);
    } else {
        // ---- W path: one output column o per block ----
        const int o = bid - TOKENS;              // 0..OUT_F-1
        __shared__ float srw;
        float wm = 0.f;
        if (t < GCOUNT) {                        // 32 lanes, one group each
            float s = sc[(size_t)t * OUT_F + o];
            int z = qz[(size_t)t * OUT_F + o];
            wm = s * (float)max(z, 15 - z);
        }
#pragma unroll
        for (int off = 16; off >= 1; off >>= 1)  // xor<32 stays within lanes 0..31
            wm = fmaxf(wm, __shfl_xor(wm, off));
        if (t == 0) {
            srw = 127.0f / wm;
            sw[o] = wm * (1.0f / 127.0f);
        }
        __syncthreads();
        const float rwv = srw;
#pragma unroll
        for (int ii = 0; ii < 2; ++ii) {
            int p = ii * 256 + t;                // pack within column, 0..511
            int g = p >> 4;
            int z = qz[(size_t)g * OUT_F + o];
            float f = sc[(size_t)g * OUT_F + o] * rwv;
            int w = qw[(size_t)o * PACKS + p];
            int lo = 0, hi = 0;
#pragma unroll
            for (int j = 0; j < 4; ++j) {
                int d = __float2int_rn((float)(((w >> (4 * j)) & 15) - z) * f);
                d = max(-127, min(127, d));
                lo |= (d & 255) << (8 * j);
            }
#pragma unroll
            for (int j = 4; j < 8; ++j) {
                int d = __float2int_rn((float)(((w >> (4 * j)) & 15) - z) * f);
                d = max(-127, min(127, d));
                hi |= (d & 255) << (8 * (j - 4));
            }
            ((int2*)wq)[(size_t)o * PACKS + p] = make_int2(lo, hi);
        }
    }
}

// ---------------- staging: i8 tile 256 rows x 128, 16B chunks, XOR-swizzled source ----------------
// LDS position (r, c) holds logical chunk c ^ (r&7); reader applies the same XOR.
__device__ __forceinline__ void stage_i8(const signed char* __restrict__ G, int grow0,
                                         int kt, signed char* lds, int tid) {
#pragma unroll
    for (int i = 0; i < 4; ++i) {
        int CH = i * 512 + tid;                  // chunk 0..2047
        int r = CH >> 3;
        int c = (CH & 7) ^ (r & 7);              // inverse swizzle on SOURCE
        const signed char* g = G + (size_t)(grow0 + r) * IN_F + kt + c * 16;
        __builtin_amdgcn_global_load_lds((const AS1 void*)g,
                                         (AS3 void*)(lds + CH * 16), 16, 0, 0);
    }
}

#define QUADI(AF, BF, AO, BO)                                                   \
    __builtin_amdgcn_s_setprio(1);                                              \
    _Pragma("unroll") for (int m = 0; m < 4; ++m)                               \
    _Pragma("unroll") for (int n = 0; n < 2; ++n)                               \
    _Pragma("unroll") for (int ks = 0; ks < 2; ++ks)                            \
        iacc[(AO) + m][(BO) + n] = __builtin_amdgcn_mfma_i32_16x16x64_i8(       \
            AF[m][ks], BF[n][ks], iacc[(AO) + m][(BO) + n], 0, 0, 0);           \
    __builtin_amdgcn_s_setprio(0);

// ---------------- i8 GEMM: 256x256, BK=128, 2 barriers/K-tile (settled best, r17) ----------------
// Quads: Q0=(m0-3,n0-1) Q1=(m0-3,n2-3) Q2=(m4-7,n0-1) Q3=(m4-7,n2-3), 16 MFMA each.
// Q2/Q3 of tile t run in sub0/sub1 of tile t+1 (read-ahead).
// Fence (a): afB read BEFORE bfB in sub2, so lgkmcnt(4) drains exactly the As[cab]
// readers while bfB(4) stays in flight (consumed by own-wave Q1 before fence (b)).
// Fence (b): vmcnt(4) => A(t+1),B(t+1) landed; A(t+2) in flight.
__global__ __launch_bounds__(512, 2) void gemm_i8_kernel(const signed char* __restrict__ A,
                                                         const signed char* __restrict__ B,
                                                         const float* __restrict__ sw,
                                                         const float* __restrict__ sx,
                                                         float* __restrict__ C) {
    __shared__ signed char As[2][BM * BK];   // 2 x 32 KB
    __shared__ signed char Bs[2][BN * BK];   // 2 x 32 KB (128 KB total)

    const int nbn = OUT_F / BN;              // 43
    const int nwg = (TOKENS / BM) * nbn;     // 688 = 8*86
    const int cpx = nwg >> 3;
    int bid = blockIdx.x;
    int swzb = (bid & 7) * cpx + (bid >> 3); // XCD-contiguous (bijective)
    int bm = swzb / nbn, bn = swzb % nbn;
    const int row0 = bm * BM, col0 = bn * BN;

    const int tid = threadIdx.x;
    const int lane = tid & 63;
    const int wid = tid >> 6;                // 8 waves: 2M x 4N
    const int wm = wid >> 2, wn = wid & 3;
    const int l15 = lane & 15, lhi = lane >> 4, l7 = lane & 7;
    const int cs0 = ((lhi ^ l7) & 7) * 16;        // ks0 chunk byte offset
    const int cs1 = (((4 + lhi) ^ l7) & 7) * 16;  // ks1
    const int rdA = (wm * 128 + l15) * BK;        // bytes; + m*2048 + cs
    const int rdB = (wn * 64 + l15) * BK;         // bytes; + n*2048 + cs

    i32x4 iacc[8][4] = {};
    i32x4 afA[4][2], afB[4][2], bfA[2][2], bfB[2][2];

    // prologue: A(0)->As[0], B(0)->Bs[0], A(1)->As[1]; A0,B0 landed, A1 in flight
    stage_i8(A, row0, 0, &As[0][0], tid);
    stage_i8(B, col0, 0, &Bs[0][0], tid);
    stage_i8(A, row0, BK, &As[1][0], tid);
    asm volatile("s_waitcnt vmcnt(4)" ::: "memory");
    __builtin_amdgcn_s_barrier();

    for (int t = 0; t < NKT; ++t) {
        const int cab = t & 1;
        const signed char* At = &As[cab][0];
        const signed char* Bt = &Bs[cab][0];

        // ---- sub0: read afA(t); stage B(t+1)->Bs[cab^1]; MFMA Q2(t-1) ----
#pragma unroll
        for (int m = 0; m < 4; ++m) {
            afA[m][0] = *(const i32x4*)(At + rdA + m * 2048 + cs0);
            afA[m][1] = *(const i32x4*)(At + rdA + m * 2048 + cs1);
        }
        if (t + 1 < NKT) stage_i8(B, col0, (t + 1) * BK, &Bs[cab ^ 1][0], tid);
        __builtin_amdgcn_sched_barrier(0);
        if (t > 0) { QUADI(afB, bfA, 4, 0); }

        // ---- sub1: read bfA(t); MFMA Q3(t-1) ----
#pragma unroll
        for (int n = 0; n < 2; ++n) {
            bfA[n][0] = *(const i32x4*)(Bt + rdB + n * 2048 + cs0);
            bfA[n][1] = *(const i32x4*)(Bt + rdB + n * 2048 + cs1);
        }
        __builtin_amdgcn_sched_barrier(0);
        if (t > 0) { QUADI(afB, bfB, 4, 2); }

        // ---- sub2: read afB(t) FIRST, then bfB(t); MFMA Q0(t); fence (a)=lgkmcnt(4) ----
#pragma unroll
        for (int m = 0; m < 4; ++m) {
            afB[m][0] = *(const i32x4*)(At + rdA + (4 + m) * 2048 + cs0);
            afB[m][1] = *(const i32x4*)(At + rdA + (4 + m) * 2048 + cs1);
        }
#pragma unroll
        for (int n = 0; n < 2; ++n) {
            bfB[n][0] = *(const i32x4*)(Bt + rdB + (2 + n) * 2048 + cs0);
            bfB[n][1] = *(const i32x4*)(Bt + rdB + (2 + n) * 2048 + cs1);
        }
        __builtin_amdgcn_sched_barrier(0);
        QUADI(afA, bfA, 0, 0);
        asm volatile("s_waitcnt lgkmcnt(4)" ::: "memory");   // drain afB; bfB may fly
        __builtin_amdgcn_sched_barrier(0);
        __builtin_amdgcn_s_barrier();

        // ---- sub3: stage A(t+2)->As[cab]; MFMA Q1(t); fence (b) ----
        if (t + 2 < NKT) stage_i8(A, row0, (t + 2) * BK, &As[cab][0], tid);
        __builtin_amdgcn_sched_barrier(0);
        QUADI(afA, bfB, 0, 2);
        if (t < NKT - 2) {
            asm volatile("s_waitcnt vmcnt(4)" ::: "memory");   // t+1 landed; A(t+2) in flight
        } else if (t == NKT - 2) {
            asm volatile("s_waitcnt vmcnt(0)" ::: "memory");
        }
        __builtin_amdgcn_s_barrier();
    }

    // ---- pipeline tail: Q2(31), Q3(31) ----
    { QUADI(afB, bfA, 4, 0); }
    { QUADI(afB, bfB, 4, 2); }

    // ---- epilogue: C = sx[row] * Sw[col] * iacc ----
#pragma unroll
    for (int m = 0; m < 8; ++m) {
        const int rbase = row0 + wm * 128 + m * 16 + lhi * 4;
        f32x4 s4 = *(const f32x4*)(sx + rbase);
#pragma unroll
        for (int n = 0; n < 4; ++n) {
            const int c = col0 + wn * 64 + n * 16 + l15;
            const float swc = sw[c];
#pragma unroll
            for (int j = 0; j < 4; ++j)
                C[(size_t)(rbase + j) * OUT_F + c] = s4[j] * swc * (float)iacc[m][n][j];
        }
    }
}

// ---------------- fallback: fused dequant GEMM (128-tile bf16, known-good) ----------------
__device__ __forceinline__ void mfma_tile128(const short* As, const short* Bs,
                                             f32x4 acc[4][4], int lane, int wm, int wn) {
#pragma unroll
    for (int kk = 0; kk < 64; kk += 32) {
        const int kb = kk + (lane >> 4) * 8;
        bf16x8 af[4], bfr[4];
#pragma unroll
        for (int m = 0; m < 4; ++m) {
            int r = wm * 64 + m * 16 + (lane & 15);
            af[m] = *(const bf16x8*)(As + r * 64 + kb);
        }
#pragma unroll
        for (int n = 0; n < 4; ++n) {
            int c = wn * 64 + n * 16 + (lane & 15);
            bfr[n] = *(const bf16x8*)(Bs + c * 64 + kb);
        }
#pragma unroll
        for (int m = 0; m < 4; ++m)
#pragma unroll
            for (int n = 0; n < 4; ++n)
                acc[m][n] = __builtin_amdgcn_mfma_f32_16x16x32_bf16(af[m], bfr[n],
                                                                    acc[m][n], 0, 0, 0);
    }
}

__global__ __launch_bounds__(256) void gemm_fused_kernel(const float* __restrict__ x,
                                                         const int* __restrict__ qw,
                                                         const int* __restrict__ qz,
                                                         const float* __restrict__ sc,
                                                         float* __restrict__ C) {
    const int nbn = OUT_F / 128;
    const int nwg = (TOKENS / 128) * nbn;
    const int cpx = nwg >> 3;
    int bid = blockIdx.x;
    int swzb = (bid & 7) * cpx + (bid >> 3);
    int bm = swzb / nbn, bn = swzb % nbn;
    const int row0 = bm * 128, col0 = bn * 128;

    __shared__ short As[128 * 64];
    __shared__ short Bs[128 * 64];

    const int tid = threadIdx.x;
    const int lane = tid & 63;
    const int wid = tid >> 6;
    const int wm = wid >> 1, wn = wid & 1;

    f32x4 acc[4][4] = {};

    for (int kt = 0; kt < IN_F; kt += 64) {
#pragma unroll
        for (int i = 0; i < 4; ++i) {
            int idx = i * 256 + tid;
            int r = idx >> 3, kc = (idx & 7) * 8;
            const float4* src = (const float4*)(x + (size_t)(row0 + r) * IN_F + kt + kc);
            float4 aa = src[0], bb = src[1];
            bf16x8 v;
            v[0] = f2bf(aa.x); v[1] = f2bf(aa.y); v[2] = f2bf(aa.z); v[3] = f2bf(aa.w);
            v[4] = f2bf(bb.x); v[5] = f2bf(bb.y); v[6] = f2bf(bb.z); v[7] = f2bf(bb.w);
            *(bf16x8*)(As + r * 64 + kc) = v;
        }
        {
            int ol = tid >> 1;
            int kc = (tid & 1) * 32;
            const int4* src = (const int4*)(qw + (size_t)(col0 + ol) * PACKS + ((kt + kc) >> 3));
            int4 w4 = *src;
            int g = kt >> 7;
            float z = (float)qz[(size_t)g * OUT_F + col0 + ol];
            float s = sc[(size_t)g * OUT_F + col0 + ol];
            float zs = z * s;
            const int* wp = (const int*)&w4;
#pragma unroll
            for (int c2 = 0; c2 < 4; ++c2) {
                int w32 = wp[c2];
                bf16x8 v;
#pragma unroll
                for (int j = 0; j < 8; ++j)
                    v[j] = f2bf((float)((w32 >> (4 * j)) & 15) * s - zs);
                *(bf16x8*)(Bs + ol * 64 + kc + c2 * 8) = v;
            }
        }
        __syncthreads();
        mfma_tile128(As, Bs, acc, lane, wm, wn);
        __syncthreads();
    }
#pragma unroll
    for (int m = 0; m < 4; ++m)
#pragma unroll
        for (int n = 0; n < 4; ++n) {
            int r = row0 + wm * 64 + m * 16 + ((lane >> 4) << 2);
            int c = col0 + wn * 64 + n * 16 + (lane & 15);
#pragma unroll
            for (int j = 0; j < 4; ++j)
                C[(size_t)(r + j) * OUT_F + c] = acc[m][n][j];
        }
}

extern "C" void kernel_launch(void* const* d_in, const int* in_sizes, int n_in,
                              void* d_out, int out_size, void* d_ws, size_t ws_size,
                              hipStream_t stream) {
    const float* x = (const float*)d_in[0];
    const int* qw = (const int*)d_in[1];
    const int* qz = (const int*)d_in[2];
    const float* sc = (const float*)d_in[3];
    float* out = (float*)d_out;

    const size_t xq_b = (size_t)TOKENS * IN_F;       // 16 MB
    const size_t sx_b = (size_t)TOKENS * 4;          // 16 KB
    const size_t sw_b = (size_t)OUT_F * 4;           // 44 KB
    const size_t wq_b = (size_t)OUT_F * IN_F;        // 45 MB
    const size_t need = xq_b + sx_b + sw_b + wq_b;

    if (ws_size >= need) {
        signed char* xq = (signed char*)d_ws;
        float* sx = (float*)((char*)d_ws + xq_b);
        float* sw = (float*)((char*)d_ws + xq_b + sx_b);
        signed char* wq = (signed char*)((char*)d_ws + xq_b + sx_b + sw_b);
        prep_kernel<<<TOKENS + OUT_F, 256, 0, stream>>>(x, qw, qz, sc, xq, sx, sw, wq);
        const int ngemm = (TOKENS / BM) * (OUT_F / BN);   // 688
        gemm_i8_kernel<<<ngemm, 512, 0, stream>>>(xq, wq, sw, sx, out);
    } else {
        gemm_fused_kernel<<<(TOKENS / 128) * (OUT_F / 128), 256, 0, stream>>>(x, qw, qz, sc, out);
    }
}